// Round 11
// baseline (74.566 us; speedup 1.0000x reference)
//
#include <hip/hip_runtime.h>

#define H 512
#define W 512
#define BAND 32
#define NBANDS (H / BAND)   // 16
#define NT (W / 4)          // 128 tiles per row
#define NEG_INF (-3.402823466e38f)

__global__ void zero_acc_kernel(double* acc) {
    if (threadIdx.x == 0) acc[0] = 0.0;
}

// One block per (band of 32 output rows, image, tensor); 512 threads.
// Batches of 4 s-rows: thread = (row-slot q = tid>>7, 4-col tile t = tid&127).
// Software-pipelined: batch i+1's 9 global loads (3 float4 + 6 halo scalars)
// are issued right after batch i's values are consumed, BEFORE bar1 -- they
// stay in flight across both barriers (global->reg loads don't force a vmcnt
// drain at s_barrier), hiding the L1/L2 round-trip that round 10 exposed
// (VALUBusy 21%, loads serial-between-barriers).
//  Stage A: consume prefetched rows -> s[4 cols], per-tile suffix S[4] /
//           prefix P[4] (float4) + tile max M (separate stride-4B array:
//           reading Sarr[*][0] at 16B stride was an 8-way bank conflict,
//           1.15M conflicts in round 9). Then issue prefetch(i+1). [bar]
//  Stage B: h(4t+k) = max(S_{t-2}[k], M_{t-1}, M_t, M_{t+1}, P_{t+2}[k]);
//           write h row (float4). [bar]
//  Stage C: thread = column; 4 b32 reads of hrow + register van Herk
//           (arr[16], 16-row segments), accumulate accMax.
// Virtual rows (outside [0,H)) are whole 4-row sub-phases (jlo_v % 4 == 0)
// -> skip A/B uniformly, contribute h=-inf in stage C, still issue prefetch.
// Avg-pool branch collapses to weighted sum of s (closed-form border counts).
// (512,6) caps VGPR at 85 (no forced spill -- round-8's (512,8)/64-cap
// spilled 22.5 MB); if the allocator lands <=64 we still get 8 waves/SIMD.
__global__ __launch_bounds__(512, 6) void fused_kernel(const float* __restrict__ in0,
                                                       const float* __restrict__ in1,
                                                       double* __restrict__ acc) {
    const int band = blockIdx.x;
    const int img  = blockIdx.y;
    const float* __restrict__ im = (blockIdx.z ? in1 : in0) + (size_t)img * H * W;

    const int y0 = band * BAND, y1 = y0 + BAND;
    const int jlo_v = y0 - 8;            // first streamed s-row (multiple of 4)

    __shared__ float Sarr[4][NT + 4][4]; // suffix per tile, idx = tile + 2
    __shared__ float Parr[4][NT + 4][4]; // prefix per tile
    __shared__ float Marr[4][NT + 4];    // tile max (stride-4B reads!)
    __shared__ float hrow[4][W];         // h rows of current 4-row batch
    __shared__ double wsum[8];

    const int tid = threadIdx.x;
    const int q   = tid >> 7;            // row slot 0..3
    const int t   = tid & 127;           // tile 0..127
    const int c0  = t << 2;              // first col of tile
    const int x   = tid;                 // stage-C column

    // -inf pads (indices never written by the main loop; first barrier guards):
    // S reads idx t in [0,127] -> pads 0,1; P reads idx t+4 in [4,131]
    // -> pads 130,131; M reads idx t+1,t+3 in [1,130] -> pads 1,130.
    if (t < 2) {
        *(float4*)Sarr[q][t]       = make_float4(NEG_INF, NEG_INF, NEG_INF, NEG_INF);
        *(float4*)Parr[q][130 + t] = make_float4(NEG_INF, NEG_INF, NEG_INF, NEG_INF);
        Marr[q][t]       = NEG_INF;
        Marr[q][130 + t] = NEG_INF;
    }

    // per-col horizontal window sizes for avg branch (/289)
    float cxk[4];
#pragma unroll
    for (int k = 0; k < 4; ++k) {
        const int col = c0 + k;
        const int wlo = col - 8 > 0 ? col - 8 : 0;
        const int whi = col + 8 < W - 1 ? col + 8 : W - 1;
        cxk[k] = (float)(whi - wlo + 1) * (1.f / 289.f);
    }

    // prefetch registers: rows (j0+q-1 .. j0+q+1) of the NEXT real batch.
    // All indices static after unroll (rule: runtime-indexed arrays spill).
    float4 pf[3];
    float  pl[3], pr[3];

#define ISSUE(J0)                                                           \
    {                                                                       \
        const int jj_ = (J0) + q;                                           \
        _Pragma("unroll")                                                   \
        for (int dr_ = 0; dr_ < 3; ++dr_) {                                 \
            const int rr_ = jj_ + dr_ - 1;                                  \
            if (rr_ >= 0 && rr_ < H) {                                      \
                const float* rp_ = im + (size_t)rr_ * W + c0;               \
                pf[dr_] = *(const float4*)rp_;                              \
                pl[dr_] = (c0 > 0)     ? rp_[-1] : 0.f;                     \
                pr[dr_] = (c0 + 4 < W) ? rp_[4]  : 0.f;                     \
            } else {                                                        \
                pf[dr_] = make_float4(0.f, 0.f, 0.f, 0.f);                  \
                pl[dr_] = 0.f; pr[dr_] = 0.f;                               \
            }                                                               \
        }                                                                   \
    }

    if (jlo_v >= 0) ISSUE(jlo_v);        // bands >= 1 start real

    float accMax = 0.f, accSum = 0.f;
    float arr[16];                       // van Herk: prev-seg suffix / cur h
    float hc[4];

    for (int seg = 0; seg < 3; ++seg) {
        const bool emit = (seg != 0);
        float Pblk = NEG_INF;
#pragma unroll
        for (int r4 = 0; r4 < 4; ++r4) {
            const int j0 = jlo_v + seg * 16 + r4 * 4;   // block-uniform, %4==0
            if (j0 >= 0 && j0 < H) {     // whole sub-phase real or virtual
                // ---- stage A: consume prefetched rows -> s[4] ----
                float u0 = 0.f, u1 = 0.f, u2 = 0.f, u3 = 0.f;
#pragma unroll
                for (int dr = 0; dr < 3; ++dr) {
                    u0 += pl[dr]    + pf[dr].x + pf[dr].y;
                    u1 += pf[dr].x  + pf[dr].y + pf[dr].z;
                    u2 += pf[dr].y  + pf[dr].z + pf[dr].w;
                    u3 += pf[dr].z  + pf[dr].w + pr[dr];
                }
                const float s0 = u0 * (1.f / 9.f), s1 = u1 * (1.f / 9.f);
                const float s2 = u2 * (1.f / 9.f), s3 = u3 * (1.f / 9.f);
                {
                    const int j   = j0 + q;
                    const int rlo = j - 8 > y0 ? j - 8 : y0;
                    const int rhi = j + 8 < y1 - 1 ? j + 8 : y1 - 1;
                    accSum += (s0 * cxk[0] + s1 * cxk[1] + s2 * cxk[2] + s3 * cxk[3])
                              * (float)(rhi - rlo + 1);
                }
                const float p1 = fmaxf(s0, s1), p2 = fmaxf(p1, s2), p3 = fmaxf(p2, s3);
                const float w2 = fmaxf(s3, s2), w1 = fmaxf(w2, s1), w0 = fmaxf(w1, s0);

                // ---- prefetch batch i+1 (in flight across both barriers) ----
                {
                    const int j0n = j0 + 4;
                    if (j0n < H) ISSUE(j0n);
                }

                *(float4*)Sarr[q][t + 2] = make_float4(w0, w1, w2, s3);
                *(float4*)Parr[q][t + 2] = make_float4(s0, p1, p2, p3);
                Marr[q][t + 2] = p3;
                __syncthreads();                        // bar1: S/P/M ready

                // ---- stage B: combine tiles -> h ----
                const float4 Sv = *(const float4*)Sarr[q][t];      // tile t-2
                const float4 Pv = *(const float4*)Parr[q][t + 4];  // tile t+2
                const float mm = fmaxf(fmaxf(Marr[q][t + 1], p3), Marr[q][t + 3]);
                const float h0 = fmaxf(fmaxf(Sv.x, mm), Pv.x);
                const float h1 = fmaxf(fmaxf(Sv.y, mm), Pv.y);
                const float h2 = fmaxf(fmaxf(Sv.z, mm), Pv.z);
                const float h3 = fmaxf(fmaxf(Sv.w, mm), Pv.w);
                *(float4*)&hrow[q][c0] = make_float4(h0, h1, h2, h3);
                __syncthreads();                        // bar2: hrow ready

                hc[0] = hrow[0][x]; hc[1] = hrow[1][x];
                hc[2] = hrow[2][x]; hc[3] = hrow[3][x];
            } else {
                // virtual sub-phase: keep the pipeline primed at the leading edge
                const int j0n = j0 + 4;
                if (j0n >= 0 && j0n < H) ISSUE(j0n);
                hc[0] = hc[1] = hc[2] = hc[3] = NEG_INF;
            }
            // ---- stage C: vertical van Herk ingest + emit (registers) ----
#pragma unroll
            for (int qq = 0; qq < 4; ++qq) {
                const int p = r4 * 4 + qq;              // static index
                const float h = hc[qq];
                Pblk = fmaxf(Pblk, h);
                if (emit) accMax += fmaxf(arr[p], Pblk);
                arr[p] = h;
            }
        }
        // segment end: in-place suffix transform arr[p] = max(h[p..15])
#pragma unroll
        for (int r = 14; r >= 0; --r) arr[r] = fmaxf(arr[r], arr[r + 1]);
    }
#undef ISSUE

    // ---- block reduction ----
    double v = (double)(accMax - accSum);
#pragma unroll
    for (int off = 32; off > 0; off >>= 1) v += __shfl_down(v, off, 64);
    const int lane = tid & 63, wave = tid >> 6;
    if (lane == 0) wsum[wave] = v;
    __syncthreads();
    if (tid == 0) {
        double b = 0.0;
#pragma unroll
        for (int wv = 0; wv < 8; ++wv) b += wsum[wv];
        atomicAdd(acc, b);
    }
}

__global__ void finalize_kernel(const double* __restrict__ acc, float* __restrict__ out) {
    if (threadIdx.x == 0) {
        // total pixels across both tensors = 2*32*512*512 = 16777216
        out[0] = (float)(1.0 - acc[0] * (1.0 / 16777216.0));
    }
}

extern "C" void kernel_launch(void* const* d_in, const int* in_sizes, int n_in,
                              void* d_out, int out_size, void* d_ws, size_t ws_size,
                              hipStream_t stream) {
    const float* in0 = (const float*)d_in[0];
    const float* in1 = (const float*)d_in[1];
    float* out = (float*)d_out;
    double* acc = (double*)d_ws;

    zero_acc_kernel<<<1, 64, 0, stream>>>(acc);
    fused_kernel<<<dim3(NBANDS, 32, 2), 512, 0, stream>>>(in0, in1, acc);
    finalize_kernel<<<1, 64, 0, stream>>>(acc, out);
}

// Round 12
// 52.820 us; speedup vs baseline: 1.4117x; 1.4117x over previous
//
#include <hip/hip_runtime.h>

#define H 512
#define W 512
#define BAND 32
#define NBANDS (H / BAND)   // 16
#define NEG_INF (-3.402823466e38f)

__global__ void zero_acc_kernel(double* acc) {
    if (threadIdx.x == 0) acc[0] = 0.0;
}

// One block per (band of 32 output rows, image, tensor); 512 threads = 8 waves.
// Each WAVE owns one full s-row per batch (64 lanes x 8 cols = 512 cols), so the
// horizontal 17-max is wave-local (shuffles), no LDS/barriers:
//   per lane: t[k] = 3-row vertical raw sum (6 float4 loads, L1-served),
//             s[k] = t[k-1]+t[k]+t[k+1]  (2 halo shuffles; 9x-scaled, /9 at end),
//             tile prefix p[k], running suffix qrun, tile max m;
//   h(8L+k) = max( q_{L-1}[k] [shfl_up], m_L, p_{L+1}[k] [shfl_down] )  -- exact.
// Vertical 17-max: 8 h-rows/batch -> double-buffered hbuf (ONE barrier per
// batch; writer of buf[b^1] never races readers of buf[b]), then per-column
// register van Herk (arr[16], 16-row segments = 2 batches).
// hbuf split-half layout: lane's k=0..3 at [4L], k=4..7 at [256+4L] -> both the
// float4 writes (16B lane stride) and the column reads (pos precomputed) are
// conflict-free. Batch loop fully unrolled -> all arr indices static (no scratch).
// Avg-pool branch collapses to weighted sum of s (closed-form border counts).
__global__ __launch_bounds__(512, 8) void fused_kernel(const float* __restrict__ in0,
                                                       const float* __restrict__ in1,
                                                       double* __restrict__ acc) {
    const int band = blockIdx.x;
    const int img  = blockIdx.y;
    const float* __restrict__ im = (blockIdx.z ? in1 : in0) + (size_t)img * H * W;

    const int y0 = band * BAND, y1 = y0 + BAND;
    const int jlo_v = y0 - 8;            // first streamed s-row (multiple of 8)

    __shared__ float hbuf[2][8][W];      // double-buffered h rows (split-half)
    __shared__ double wsum[8];

    const int tid  = threadIdx.x;
    const int w    = tid >> 6;           // wave = row slot 0..7
    const int lane = tid & 63;
    const int c0   = lane << 3;          // 8 cols per lane
    const int x    = tid;                // stage-C column
    // split-half position of column x inside an hbuf row
    const int pos  = ((x & 4) ? 256 : 0) + ((x >> 3) << 2) + (x & 3);

    float accMax = 0.f, accSum = 0.f;
    float arr[16];                       // van Herk: prev-seg suffix / cur h
    float Pblk = NEG_INF;

#pragma unroll
    for (int b = 0; b < 6; ++b) {        // 6 batches of 8 s-rows
        const int j = jlo_v + b * 8 + w; // this wave's s-row (wave-uniform)
        float h[8];
        if (j >= 0 && j < H) {
            // ---- raw: vertical 3-row sum t[8] ----
            float t[8];
#pragma unroll
            for (int k = 0; k < 8; ++k) t[k] = 0.f;
#pragma unroll
            for (int dr = -1; dr <= 1; ++dr) {
                const int r = j + dr;
                if (r >= 0 && r < H) {   // wave-uniform
                    const float* rp = im + (size_t)r * W + c0;
                    const float4 a  = *(const float4*)rp;
                    const float4 c4 = *(const float4*)(rp + 4);
                    t[0] += a.x;  t[1] += a.y;  t[2] += a.z;  t[3] += a.w;
                    t[4] += c4.x; t[5] += c4.y; t[6] += c4.z; t[7] += c4.w;
                }
            }
            // ---- horizontal 3-sum: s = t[k-1]+t[k]+t[k+1] (9x-scaled) ----
            float tl = __shfl_up(t[7], 1);   if (lane == 0)  tl = 0.f;
            float tr = __shfl_down(t[0], 1); if (lane == 63) tr = 0.f;
            float s[8];
            s[0] = tl + t[0] + t[1];
#pragma unroll
            for (int k = 1; k < 7; ++k) s[k] = t[k - 1] + t[k] + t[k + 1];
            s[7] = t[6] + t[7] + tr;

            // ---- avg branch: weighted sum of s ----
            const int rlo = (j - 8 > y0) ? j - 8 : y0;
            const int rhi = (j + 8 < y1 - 1) ? j + 8 : y1 - 1;
            float rowsum = 0.f;
#pragma unroll
            for (int k = 0; k < 8; ++k) {
                const int col = c0 + k;
                const int wlo = (col - 8 > 0) ? col - 8 : 0;
                const int whi = (col + 8 < W - 1) ? col + 8 : W - 1;
                rowsum += s[k] * (float)(whi - wlo + 1);
            }
            accSum += rowsum * ((float)(rhi - rlo + 1) * (1.f / 289.f));

            // ---- horizontal 17-max via tile prefix/suffix + lane shuffles ----
            float p[8];
            p[0] = s[0];
#pragma unroll
            for (int k = 1; k < 8; ++k) p[k] = fmaxf(p[k - 1], s[k]);
            const float m = p[7];
            float qrun = s[7];
#pragma unroll
            for (int k = 7; k >= 0; --k) {
                if (k < 7) qrun = fmaxf(qrun, s[k]);
                float qp = __shfl_up(qrun, 1);   if (lane == 0)  qp = NEG_INF;
                float pn = __shfl_down(p[k], 1); if (lane == 63) pn = NEG_INF;
                h[k] = fmaxf(fmaxf(qp, m), pn);
            }
        } else {
#pragma unroll
            for (int k = 0; k < 8; ++k) h[k] = NEG_INF;   // virtual row
        }
        // ---- publish h row (split-half, conflict-free) ----
        {
            float* hw = &hbuf[b & 1][w][0];
            *(float4*)&hw[lane << 2]         = make_float4(h[0], h[1], h[2], h[3]);
            *(float4*)&hw[256 + (lane << 2)] = make_float4(h[4], h[5], h[6], h[7]);
        }
        __syncthreads();                 // the ONLY barrier per batch

        // ---- stage C: vertical van Herk over this batch's 8 rows ----
        {
            const float* hb = &hbuf[b & 1][0][0];
            if ((b & 1) == 0) Pblk = NEG_INF;   // new 16-row segment
#pragma unroll
            for (int r = 0; r < 8; ++r) {
                const float hv = hb[r * W + pos];
                const int pp = (b & 1) * 8 + r; // static after unroll
                Pblk = fmaxf(Pblk, hv);
                if (b >= 2) accMax += fmaxf(arr[pp], Pblk);
                arr[pp] = hv;
            }
            if (b & 1) {                 // segment end: suffix transform
#pragma unroll
                for (int rr = 14; rr >= 0; --rr) arr[rr] = fmaxf(arr[rr], arr[rr + 1]);
            }
        }
    }

    // ---- block reduction (values are 9x-scaled; undo once) ----
    double v = ((double)accMax - (double)accSum) * (1.0 / 9.0);
#pragma unroll
    for (int off = 32; off > 0; off >>= 1) v += __shfl_down(v, off, 64);
    const int lane2 = tid & 63, wave2 = tid >> 6;
    if (lane2 == 0) wsum[wave2] = v;
    __syncthreads();
    if (tid == 0) {
        double bsum = 0.0;
#pragma unroll
        for (int wv = 0; wv < 8; ++wv) bsum += wsum[wv];
        atomicAdd(acc, bsum);
    }
}

__global__ void finalize_kernel(const double* __restrict__ acc, float* __restrict__ out) {
    if (threadIdx.x == 0) {
        // total pixels across both tensors = 2*32*512*512 = 16777216
        out[0] = (float)(1.0 - acc[0] * (1.0 / 16777216.0));
    }
}

extern "C" void kernel_launch(void* const* d_in, const int* in_sizes, int n_in,
                              void* d_out, int out_size, void* d_ws, size_t ws_size,
                              hipStream_t stream) {
    const float* in0 = (const float*)d_in[0];
    const float* in1 = (const float*)d_in[1];
    float* out = (float*)d_out;
    double* acc = (double*)d_ws;

    zero_acc_kernel<<<1, 64, 0, stream>>>(acc);
    fused_kernel<<<dim3(NBANDS, 32, 2), 512, 0, stream>>>(in0, in1, acc);
    finalize_kernel<<<1, 64, 0, stream>>>(acc, out);
}

// Round 13
// 41.946 us; speedup vs baseline: 1.7777x; 1.2592x over previous
//
#include <hip/hip_runtime.h>

#define H 512
#define W 512
#define BAND 32
#define NBANDS (H / BAND)   // 16
#define NEG_INF (-3.402823466e38f)

__global__ void zero_acc_kernel(double* acc) {
    if (threadIdx.x == 0) acc[0] = 0.0;
}

// One block per (band of 32 output rows, image, tensor); 512 threads = 8 waves.
// Each WAVE owns one full s-row per batch (64 lanes x 8 cols); horizontal 17-max
// is wave-local via tile prefix/suffix + 16 lane shuffles (no LDS, no barriers).
// Vertical 17-max: 8 h-rows/batch -> double-buffered hbuf, ONE barrier per
// batch, then per-column register van Herk (arr[16], 16-row segments).
// vs round 12 (same algebra, absmax 0): the 6-batch full unroll let the
// scheduler hoist later batches' global loads -> liveness > 64-VGPR cap ->
// 55 MB scratch spill (WRITE_SIZE tell) + 28 MB extra FETCH. Fix: outer
// `#pragma unroll 1` loop over 3 segment-pairs; each pair inlines one even +
// one odd batch (literal hbuf index -> static arr/hbuf indexing), transients
// scoped per batch, barrier between batches fences load hoisting.
// hbuf split-half layout: lane's k=0..3 at [4L], k=4..7 at [256+4L]; the 786K
// "bank conflicts" in round 12 are exactly the 16 shuffles/batch/wave
// (ds_permute bookkeeping), not a layout conflict.
__global__ __launch_bounds__(512, 8) void fused_kernel(const float* __restrict__ in0,
                                                       const float* __restrict__ in1,
                                                       double* __restrict__ acc) {
    const int band = blockIdx.x;
    const int img  = blockIdx.y;
    const float* __restrict__ im = (blockIdx.z ? in1 : in0) + (size_t)img * H * W;

    const int y0 = band * BAND, y1 = y0 + BAND;
    const int jlo_v = y0 - 8;            // first streamed s-row (multiple of 8)

    __shared__ float hbuf[2][8][W];      // double-buffered h rows (split-half)
    __shared__ double wsum[8];

    const int tid  = threadIdx.x;
    const int w    = tid >> 6;           // wave = row slot 0..7
    const int lane = tid & 63;
    const int c0   = lane << 3;          // 8 cols per lane
    // split-half position of column tid inside an hbuf row
    const int pos  = ((tid & 4) ? 256 : 0) + ((tid >> 3) << 2) + (tid & 3);

    float accMax = 0.f, accSum = 0.f;
    float arr[16];                       // van Herk: prev-seg suffix / cur h
    float Pblk = NEG_INF;

// One 8-row batch. BVAL = batch index (runtime ok), BUF = literal 0/1.
#define PROCESS(BVAL, BUF)                                                     \
    {                                                                          \
        const int j = jlo_v + (BVAL) * 8 + w;   /* wave-uniform s-row */       \
        float h[8];                                                            \
        if (j >= 0 && j < H) {                                                 \
            float t[8];                                                        \
            _Pragma("unroll") for (int k = 0; k < 8; ++k) t[k] = 0.f;          \
            _Pragma("unroll") for (int dr = -1; dr <= 1; ++dr) {               \
                const int r = j + dr;                                          \
                if (r >= 0 && r < H) {          /* wave-uniform */             \
                    const float* rp = im + (size_t)r * W + c0;                 \
                    const float4 a  = *(const float4*)rp;                      \
                    const float4 c4 = *(const float4*)(rp + 4);                \
                    t[0] += a.x;  t[1] += a.y;  t[2] += a.z;  t[3] += a.w;     \
                    t[4] += c4.x; t[5] += c4.y; t[6] += c4.z; t[7] += c4.w;    \
                }                                                              \
            }                                                                  \
            float tl = __shfl_up(t[7], 1);   if (lane == 0)  tl = 0.f;         \
            float tr = __shfl_down(t[0], 1); if (lane == 63) tr = 0.f;         \
            float s[8];                                                        \
            s[0] = tl + t[0] + t[1];                                           \
            _Pragma("unroll") for (int k = 1; k < 7; ++k)                      \
                s[k] = t[k - 1] + t[k] + t[k + 1];                             \
            s[7] = t[6] + t[7] + tr;                                           \
            const int rlo = (j - 8 > y0) ? j - 8 : y0;                         \
            const int rhi = (j + 8 < y1 - 1) ? j + 8 : y1 - 1;                 \
            float rowsum = 0.f;                                                \
            _Pragma("unroll") for (int k = 0; k < 8; ++k) {                    \
                const int col = c0 + k;                                        \
                const int wlo = (col - 8 > 0) ? col - 8 : 0;                   \
                const int whi = (col + 8 < W - 1) ? col + 8 : W - 1;           \
                rowsum += s[k] * (float)(whi - wlo + 1);                       \
            }                                                                  \
            accSum += rowsum * ((float)(rhi - rlo + 1) * (1.f / 289.f));       \
            float p[8];                                                        \
            p[0] = s[0];                                                       \
            _Pragma("unroll") for (int k = 1; k < 8; ++k)                      \
                p[k] = fmaxf(p[k - 1], s[k]);                                  \
            const float m = p[7];                                              \
            float qrun = s[7];                                                 \
            _Pragma("unroll") for (int k = 7; k >= 0; --k) {                   \
                if (k < 7) qrun = fmaxf(qrun, s[k]);                           \
                float qp = __shfl_up(qrun, 1);   if (lane == 0)  qp = NEG_INF; \
                float pn = __shfl_down(p[k], 1); if (lane == 63) pn = NEG_INF; \
                h[k] = fmaxf(fmaxf(qp, m), pn);                                \
            }                                                                  \
        } else {                                                               \
            _Pragma("unroll") for (int k = 0; k < 8; ++k) h[k] = NEG_INF;      \
        }                                                                      \
        {                                                                      \
            float* hw = &hbuf[BUF][w][0];                                      \
            *(float4*)&hw[lane << 2]         = make_float4(h[0], h[1], h[2], h[3]); \
            *(float4*)&hw[256 + (lane << 2)] = make_float4(h[4], h[5], h[6], h[7]); \
        }                                                                      \
        __syncthreads();                 /* the ONLY barrier per batch */      \
        {                                                                      \
            const float* hb = &hbuf[BUF][0][0];                                \
            if ((BUF) == 0) Pblk = NEG_INF;      /* new 16-row segment */      \
            _Pragma("unroll") for (int r = 0; r < 8; ++r) {                    \
                const float hv = hb[r * W + pos];                              \
                const int pp = (BUF) * 8 + r;    /* static */                  \
                Pblk = fmaxf(Pblk, hv);                                        \
                if (emit) accMax += fmaxf(arr[pp], Pblk);                      \
                arr[pp] = hv;                                                  \
            }                                                                  \
        }                                                                      \
    }

#pragma unroll 1
    for (int sp = 0; sp < 3; ++sp) {     // 3 segment-pairs = 6 batches
        const bool emit = (sp != 0);     // outputs exist from batch 2 on
        PROCESS(2 * sp, 0)
        PROCESS(2 * sp + 1, 1)
        // segment end: in-place suffix transform arr[p] = max(h[p..15])
#pragma unroll
        for (int rr = 14; rr >= 0; --rr) arr[rr] = fmaxf(arr[rr], arr[rr + 1]);
    }
#undef PROCESS

    // ---- block reduction (values are 9x-scaled; undo once) ----
    double v = ((double)accMax - (double)accSum) * (1.0 / 9.0);
#pragma unroll
    for (int off = 32; off > 0; off >>= 1) v += __shfl_down(v, off, 64);
    if (lane == 0) wsum[w] = v;
    __syncthreads();
    if (tid == 0) {
        double bsum = 0.0;
#pragma unroll
        for (int wv = 0; wv < 8; ++wv) bsum += wsum[wv];
        atomicAdd(acc, bsum);
    }
}

__global__ void finalize_kernel(const double* __restrict__ acc, float* __restrict__ out) {
    if (threadIdx.x == 0) {
        // total pixels across both tensors = 2*32*512*512 = 16777216
        out[0] = (float)(1.0 - acc[0] * (1.0 / 16777216.0));
    }
}

extern "C" void kernel_launch(void* const* d_in, const int* in_sizes, int n_in,
                              void* d_out, int out_size, void* d_ws, size_t ws_size,
                              hipStream_t stream) {
    const float* in0 = (const float*)d_in[0];
    const float* in1 = (const float*)d_in[1];
    float* out = (float*)d_out;
    double* acc = (double*)d_ws;

    zero_acc_kernel<<<1, 64, 0, stream>>>(acc);
    fused_kernel<<<dim3(NBANDS, 32, 2), 512, 0, stream>>>(in0, in1, acc);
    finalize_kernel<<<1, 64, 0, stream>>>(acc, out);
}

// Round 14
// 36.246 us; speedup vs baseline: 2.0572x; 1.1573x over previous
//
#include <hip/hip_runtime.h>

#define H 512
#define W 512
#define BAND 64
#define NBANDS (H / BAND)   // 8
#define NEG_INF (-3.402823466e38f)

__global__ void zero_acc_kernel(double* acc) {
    if (threadIdx.x == 0) acc[0] = 0.0;
}

// One block per (band of 64 output rows, image, tensor); 512 threads = 8 waves.
// Each WAVE owns one full s-row per batch (64 lanes x 8 cols); horizontal 17-max
// is wave-local via tile prefix/suffix + 16 lane shuffles (no LDS, no barriers).
// Vertical 17-max: 8 h-rows/batch -> double-buffered hbuf, ONE barrier per
// batch, then per-column register van Herk (arr[16], 16-row segments).
// Lessons carried: (R12) full unroll -> load hoisting -> 55MB spill; fix is
// `#pragma unroll 1` over segment-pairs with literal buffer indices. (R13)
// (512,8)'s 64-VGPR cap still spilled 3 dwords/thread (WRITE_SIZE 6.2MB,
// VGPR reads 32) -> relax to (512,4): 128-reg cap, ~60 live, zero spill;
// grid 512 blocks = 2/CU so residency is unchanged by the relaxed cap.
// BAND=64 cuts halo redundancy: 80 streamed s-rows per 64 outputs (1.25x)
// vs 48/32 (1.5x) -> 17% less work and fetch.
// hbuf split-half layout: lane's k=0..3 at [4L], k=4..7 at [256+4L]; both the
// float4 writes and per-column reads are bank-conflict-free (the ~740K
// SQ_LDS_BANK_CONFLICT is shuffle (ds_permute) bookkeeping, not a layout bug).
__global__ __launch_bounds__(512, 4) void fused_kernel(const float* __restrict__ in0,
                                                       const float* __restrict__ in1,
                                                       double* __restrict__ acc) {
    const int band = blockIdx.x;
    const int img  = blockIdx.y;
    const float* __restrict__ im = (blockIdx.z ? in1 : in0) + (size_t)img * H * W;

    const int y0 = band * BAND, y1 = y0 + BAND;
    const int jlo_v = y0 - 8;            // first streamed s-row (multiple of 8)

    __shared__ float hbuf[2][8][W];      // double-buffered h rows (split-half)
    __shared__ double wsum[8];

    const int tid  = threadIdx.x;
    const int w    = tid >> 6;           // wave = row slot 0..7
    const int lane = tid & 63;
    const int c0   = lane << 3;          // 8 cols per lane
    // split-half position of column tid inside an hbuf row
    const int pos  = ((tid & 4) ? 256 : 0) + ((tid >> 3) << 2) + (tid & 3);

    float accMax = 0.f, accSum = 0.f;
    float arr[16];                       // van Herk: prev-seg suffix / cur h
    float Pblk = NEG_INF;

// One 8-row batch. BVAL = batch index (runtime ok), BUF = literal 0/1.
#define PROCESS(BVAL, BUF)                                                     \
    {                                                                          \
        const int j = jlo_v + (BVAL) * 8 + w;   /* wave-uniform s-row */       \
        float h[8];                                                            \
        if (j >= 0 && j < H) {                                                 \
            float t[8];                                                        \
            _Pragma("unroll") for (int k = 0; k < 8; ++k) t[k] = 0.f;          \
            _Pragma("unroll") for (int dr = -1; dr <= 1; ++dr) {               \
                const int r = j + dr;                                          \
                if (r >= 0 && r < H) {          /* wave-uniform */             \
                    const float* rp = im + (size_t)r * W + c0;                 \
                    const float4 a  = *(const float4*)rp;                      \
                    const float4 c4 = *(const float4*)(rp + 4);                \
                    t[0] += a.x;  t[1] += a.y;  t[2] += a.z;  t[3] += a.w;     \
                    t[4] += c4.x; t[5] += c4.y; t[6] += c4.z; t[7] += c4.w;    \
                }                                                              \
            }                                                                  \
            float tl = __shfl_up(t[7], 1);   if (lane == 0)  tl = 0.f;         \
            float tr = __shfl_down(t[0], 1); if (lane == 63) tr = 0.f;         \
            float s[8];                                                        \
            s[0] = tl + t[0] + t[1];                                           \
            _Pragma("unroll") for (int k = 1; k < 7; ++k)                      \
                s[k] = t[k - 1] + t[k] + t[k + 1];                             \
            s[7] = t[6] + t[7] + tr;                                           \
            const int rlo = (j - 8 > y0) ? j - 8 : y0;                         \
            const int rhi = (j + 8 < y1 - 1) ? j + 8 : y1 - 1;                 \
            float rowsum = 0.f;                                                \
            _Pragma("unroll") for (int k = 0; k < 8; ++k) {                    \
                const int col = c0 + k;                                        \
                const int wlo = (col - 8 > 0) ? col - 8 : 0;                   \
                const int whi = (col + 8 < W - 1) ? col + 8 : W - 1;           \
                rowsum += s[k] * (float)(whi - wlo + 1);                       \
            }                                                                  \
            accSum += rowsum * ((float)(rhi - rlo + 1) * (1.f / 289.f));       \
            float p[8];                                                        \
            p[0] = s[0];                                                       \
            _Pragma("unroll") for (int k = 1; k < 8; ++k)                      \
                p[k] = fmaxf(p[k - 1], s[k]);                                  \
            const float m = p[7];                                              \
            float qrun = s[7];                                                 \
            _Pragma("unroll") for (int k = 7; k >= 0; --k) {                   \
                if (k < 7) qrun = fmaxf(qrun, s[k]);                           \
                float qp = __shfl_up(qrun, 1);   if (lane == 0)  qp = NEG_INF; \
                float pn = __shfl_down(p[k], 1); if (lane == 63) pn = NEG_INF; \
                h[k] = fmaxf(fmaxf(qp, m), pn);                                \
            }                                                                  \
        } else {                                                               \
            _Pragma("unroll") for (int k = 0; k < 8; ++k) h[k] = NEG_INF;      \
        }                                                                      \
        {                                                                      \
            float* hw = &hbuf[BUF][w][0];                                      \
            *(float4*)&hw[lane << 2]         = make_float4(h[0], h[1], h[2], h[3]); \
            *(float4*)&hw[256 + (lane << 2)] = make_float4(h[4], h[5], h[6], h[7]); \
        }                                                                      \
        __syncthreads();                 /* the ONLY barrier per batch */      \
        {                                                                      \
            const float* hb = &hbuf[BUF][0][0];                                \
            if ((BUF) == 0) Pblk = NEG_INF;      /* new 16-row segment */      \
            _Pragma("unroll") for (int r = 0; r < 8; ++r) {                    \
                const float hv = hb[r * W + pos];                              \
                const int pp = (BUF) * 8 + r;    /* static */                  \
                Pblk = fmaxf(Pblk, hv);                                        \
                if (emit) accMax += fmaxf(arr[pp], Pblk);                      \
                arr[pp] = hv;                                                  \
            }                                                                  \
        }                                                                      \
    }

#pragma unroll 1
    for (int sp = 0; sp < 5; ++sp) {     // 5 segment-pairs = 10 batches
        const bool emit = (sp != 0);     // outputs exist from batch 2 on
        PROCESS(2 * sp, 0)
        PROCESS(2 * sp + 1, 1)
        // segment end: in-place suffix transform arr[p] = max(h[p..15])
#pragma unroll
        for (int rr = 14; rr >= 0; --rr) arr[rr] = fmaxf(arr[rr], arr[rr + 1]);
    }
#undef PROCESS

    // ---- block reduction (values are 9x-scaled; undo once) ----
    double v = ((double)accMax - (double)accSum) * (1.0 / 9.0);
#pragma unroll
    for (int off = 32; off > 0; off >>= 1) v += __shfl_down(v, off, 64);
    if (lane == 0) wsum[w] = v;
    __syncthreads();
    if (tid == 0) {
        double bsum = 0.0;
#pragma unroll
        for (int wv = 0; wv < 8; ++wv) bsum += wsum[wv];
        atomicAdd(acc, bsum);
    }
}

__global__ void finalize_kernel(const double* __restrict__ acc, float* __restrict__ out) {
    if (threadIdx.x == 0) {
        // total pixels across both tensors = 2*32*512*512 = 16777216
        out[0] = (float)(1.0 - acc[0] * (1.0 / 16777216.0));
    }
}

extern "C" void kernel_launch(void* const* d_in, const int* in_sizes, int n_in,
                              void* d_out, int out_size, void* d_ws, size_t ws_size,
                              hipStream_t stream) {
    const float* in0 = (const float*)d_in[0];
    const float* in1 = (const float*)d_in[1];
    float* out = (float*)d_out;
    double* acc = (double*)d_ws;

    zero_acc_kernel<<<1, 64, 0, stream>>>(acc);
    fused_kernel<<<dim3(NBANDS, 32, 2), 512, 0, stream>>>(in0, in1, acc);
    finalize_kernel<<<1, 64, 0, stream>>>(acc, out);
}

// Round 15
// 35.113 us; speedup vs baseline: 2.1236x; 1.0323x over previous
//
#include <hip/hip_runtime.h>

#define H 512
#define W 512
#define BAND 64
#define NBANDS (H / BAND)   // 8
#define NEG_INF (-3.402823466e38f)

__global__ void zero_acc_kernel(double* acc) {
    if (threadIdx.x == 0) acc[0] = 0.0;
}

// One block per (band of 64 output rows, image, tensor); 512 threads = 8 waves.
// Batches of SIXTEEN s-rows; each wave owns TWO rows (slots w and w+8) ->
// 2 independent row pipelines per wave per batch (double ILP), ONE barrier
// per 16 rows (5 per block; was 10).
// Per row (wave-local, no LDS): t[8] = 3-row vertical raw sum (6 float4,
// L1/L2-served), s = horizontal 3-sum via 2 halo shuffles (9x-scaled),
// horizontal 17-max via tile prefix/suffix + 16 lane shuffles:
//   h(8L+k) = max(S_{L-1}[k], m_L, P_{L+1}[k]).
// Vertical 17-max: batch == van Herk segment (16): publish h rows to
// double-buffered hbuf, barrier, then per-column register van Herk (arr[16],
// Pblk reset each batch, suffix transform at batch end). Output exists from
// batch 1 on. 80 streamed rows = exactly 5 batches.
// Lessons carried: (R12) full unroll -> load hoisting -> spill: outer loop
// `#pragma unroll 1`, arr indices static via unrolled r-loops. (R13) 64-VGPR
// cap spills: (512,4) = 128-reg cap; ~110 live, zero spill (WRITE_SIZE tell).
// (R14) BAND=64: 1.25x halo. hbuf split-half layout: k=0..3 at [4L],
// k=4..7 at [256+4L]; float4 writes and column reads conflict-free (the
// ~740K SQ_LDS_BANK_CONFLICT is ds_permute shuffle bookkeeping, not layout).
__global__ __launch_bounds__(512, 4) void fused_kernel(const float* __restrict__ in0,
                                                       const float* __restrict__ in1,
                                                       double* __restrict__ acc) {
    const int band = blockIdx.x;
    const int img  = blockIdx.y;
    const float* __restrict__ im = (blockIdx.z ? in1 : in0) + (size_t)img * H * W;

    const int y0 = band * BAND, y1 = y0 + BAND;
    const int jlo_v = y0 - 8;            // first streamed s-row

    __shared__ float hbuf[2][16][W];     // double-buffered h rows (split-half)
    __shared__ double wsum[8];

    const int tid  = threadIdx.x;
    const int w    = tid >> 6;           // wave id 0..7
    const int lane = tid & 63;
    const int c0   = lane << 3;          // 8 cols per lane
    // split-half position of column tid inside an hbuf row
    const int pos  = ((tid & 4) ? 256 : 0) + ((tid >> 3) << 2) + (tid & 3);

    float accMax = 0.f, accSum = 0.f;
    float arr[16];                       // van Herk: prev-seg suffix / cur h

// One s-row in slot SLOT (0..15) of batch b. j wave-uniform.
#define ROW(SLOT)                                                              \
    {                                                                          \
        const int j = jb + (SLOT);                                             \
        float h[8];                                                            \
        if (j >= 0 && j < H) {                                                 \
            float t[8];                                                        \
            _Pragma("unroll") for (int k = 0; k < 8; ++k) t[k] = 0.f;          \
            _Pragma("unroll") for (int dr = -1; dr <= 1; ++dr) {               \
                const int r = j + dr;                                          \
                if (r >= 0 && r < H) {          /* wave-uniform */             \
                    const float* rp = im + (size_t)r * W + c0;                 \
                    const float4 a  = *(const float4*)rp;                      \
                    const float4 c4 = *(const float4*)(rp + 4);                \
                    t[0] += a.x;  t[1] += a.y;  t[2] += a.z;  t[3] += a.w;     \
                    t[4] += c4.x; t[5] += c4.y; t[6] += c4.z; t[7] += c4.w;    \
                }                                                              \
            }                                                                  \
            float tl = __shfl_up(t[7], 1);   if (lane == 0)  tl = 0.f;         \
            float tr = __shfl_down(t[0], 1); if (lane == 63) tr = 0.f;         \
            float s[8];                                                        \
            s[0] = tl + t[0] + t[1];                                           \
            _Pragma("unroll") for (int k = 1; k < 7; ++k)                      \
                s[k] = t[k - 1] + t[k] + t[k + 1];                             \
            s[7] = t[6] + t[7] + tr;                                           \
            const int rlo = (j - 8 > y0) ? j - 8 : y0;                         \
            const int rhi = (j + 8 < y1 - 1) ? j + 8 : y1 - 1;                 \
            float rowsum = 0.f;                                                \
            _Pragma("unroll") for (int k = 0; k < 8; ++k) {                    \
                const int col = c0 + k;                                        \
                const int wlo = (col - 8 > 0) ? col - 8 : 0;                   \
                const int whi = (col + 8 < W - 1) ? col + 8 : W - 1;           \
                rowsum += s[k] * (float)(whi - wlo + 1);                       \
            }                                                                  \
            accSum += rowsum * ((float)(rhi - rlo + 1) * (1.f / 289.f));       \
            float p[8];                                                        \
            p[0] = s[0];                                                       \
            _Pragma("unroll") for (int k = 1; k < 8; ++k)                      \
                p[k] = fmaxf(p[k - 1], s[k]);                                  \
            const float m = p[7];                                              \
            float qrun = s[7];                                                 \
            _Pragma("unroll") for (int k = 7; k >= 0; --k) {                   \
                if (k < 7) qrun = fmaxf(qrun, s[k]);                           \
                float qp = __shfl_up(qrun, 1);   if (lane == 0)  qp = NEG_INF; \
                float pn = __shfl_down(p[k], 1); if (lane == 63) pn = NEG_INF; \
                h[k] = fmaxf(fmaxf(qp, m), pn);                                \
            }                                                                  \
        } else {                                                               \
            _Pragma("unroll") for (int k = 0; k < 8; ++k) h[k] = NEG_INF;      \
        }                                                                      \
        {                                                                      \
            float* hw = hwbase + (SLOT) * W;                                   \
            *(float4*)&hw[lane << 2]         = make_float4(h[0], h[1], h[2], h[3]); \
            *(float4*)&hw[256 + (lane << 2)] = make_float4(h[4], h[5], h[6], h[7]); \
        }                                                                      \
    }

#pragma unroll 1
    for (int b = 0; b < 5; ++b) {        // 5 batches of 16 s-rows = 80 rows
        const int jb = jlo_v + b * 16;
        float* hwbase = &hbuf[b & 1][0][0];
        ROW(w)                            // slot w
        ROW(w + 8)                        // slot w+8 (independent pipeline)
        __syncthreads();                  // the ONLY barrier per batch

        // ---- stage C: vertical van Herk over this 16-row segment ----
        const float* hb = hwbase;
        float Pblk = NEG_INF;
        if (b >= 1) {
#pragma unroll
            for (int r = 0; r < 16; ++r) {
                const float hv = hb[r * W + pos];
                Pblk = fmaxf(Pblk, hv);
                accMax += fmaxf(arr[r], Pblk);
                arr[r] = hv;
            }
        } else {
#pragma unroll
            for (int r = 0; r < 16; ++r) {
                const float hv = hb[r * W + pos];
                Pblk = fmaxf(Pblk, hv);
                arr[r] = hv;
            }
        }
        // segment end: in-place suffix transform arr[r] = max(h[r..15])
#pragma unroll
        for (int rr = 14; rr >= 0; --rr) arr[rr] = fmaxf(arr[rr], arr[rr + 1]);
    }
#undef ROW

    // ---- block reduction (values are 9x-scaled; undo once) ----
    double v = ((double)accMax - (double)accSum) * (1.0 / 9.0);
#pragma unroll
    for (int off = 32; off > 0; off >>= 1) v += __shfl_down(v, off, 64);
    if (lane == 0) wsum[w] = v;
    __syncthreads();
    if (tid == 0) {
        double bsum = 0.0;
#pragma unroll
        for (int wv = 0; wv < 8; ++wv) bsum += wsum[wv];
        atomicAdd(acc, bsum);
    }
}

__global__ void finalize_kernel(const double* __restrict__ acc, float* __restrict__ out) {
    if (threadIdx.x == 0) {
        // total pixels across both tensors = 2*32*512*512 = 16777216
        out[0] = (float)(1.0 - acc[0] * (1.0 / 16777216.0));
    }
}

extern "C" void kernel_launch(void* const* d_in, const int* in_sizes, int n_in,
                              void* d_out, int out_size, void* d_ws, size_t ws_size,
                              hipStream_t stream) {
    const float* in0 = (const float*)d_in[0];
    const float* in1 = (const float*)d_in[1];
    float* out = (float*)d_out;
    double* acc = (double*)d_ws;

    zero_acc_kernel<<<1, 64, 0, stream>>>(acc);
    fused_kernel<<<dim3(NBANDS, 32, 2), 512, 0, stream>>>(in0, in1, acc);
    finalize_kernel<<<1, 64, 0, stream>>>(acc, out);
}